// Round 19
// baseline (204.511 us; speedup 1.0000x reference)
//
#include <hip/hip_runtime.h>
#include <cstdint>

#define B_ 128
#define N_ 1024
#define D_ 16
#define U_ 128
#define M_ (B_*N_)     // 131072 rows (b,n)
#define K_ 144         // D_+U_
#define KP 192         // padded K for MFMA (6 x 32)
#define CAP 48         // ELL row capacity (~11 nnz expected; zero-filled to 48)

typedef unsigned short u16;
typedef unsigned int   u32;
typedef __attribute__((ext_vector_type(8))) short bf16x8;
typedef __attribute__((ext_vector_type(4))) float f32x4;
typedef __attribute__((ext_vector_type(2))) __fp16 h2v;   // matches builtin sigs

__device__ __forceinline__ float bf2f(u16 h){ return __uint_as_float(((u32)h) << 16); }
__device__ __forceinline__ u16 f2bf(float f){
    u32 u = __float_as_uint(f);
    return (u16)((u + 0x7FFFu + ((u >> 16) & 1u)) >> 16);
}
__device__ __forceinline__ u16 f2h(float f){
    __fp16 h = (__fp16)f; u16 s; __builtin_memcpy(&s, &h, 2); return s;
}
__device__ __forceinline__ float h2f_lo(u32 u){
    u16 s = (u16)(u & 0xFFFFu); __fp16 h; __builtin_memcpy(&h, &s, 2); return (float)h;
}
__device__ __forceinline__ float h2f_hi(u32 u){
    u16 s = (u16)(u >> 16); __fp16 h; __builtin_memcpy(&h, &s, 2); return (float)h;
}
__device__ __forceinline__ u32 pkrtz(float a, float b){
    h2v r = __builtin_amdgcn_cvt_pkrtz(a, b);
    u32 v; __builtin_memcpy(&v, &r, 4); return v;
}
__device__ __forceinline__ float sig_(float x){ return 1.0f / (1.0f + __expf(-x)); }

#if __has_builtin(__builtin_amdgcn_fdot2)
__device__ __forceinline__ float dot2_(u32 a, u32 b, float c){
    h2v av, bv; __builtin_memcpy(&av, &a, 4); __builtin_memcpy(&bv, &b, 4);
    return __builtin_amdgcn_fdot2(av, bv, c, false);
}
#else
__device__ __forceinline__ float dot2_(u32 a, u32 b, float c){
    return fmaf(h2f_hi(a), h2f_hi(b), fmaf(h2f_lo(a), h2f_lo(b), c));
}
#endif

// ------- K0 (merged): support -> ELL (f32/i32 tail + f16-packed16) ----------
__global__ void k_ellprep(const float* __restrict__ sup,
                          const float* __restrict__ kr, const float* __restrict__ kc,
                          float* __restrict__ vals, int* __restrict__ cols,
                          int* __restrict__ nnz, u32* __restrict__ packed,
                          u16* __restrict__ wr_t, u16* __restrict__ wc_t)
{
    if (blockIdx.x >= 256){
        int t = (blockIdx.x - 256) * 256 + threadIdx.x;   // 0 .. 73727
        if (t < 256*KP){
            int col = t / KP, k = t % KP;
            wr_t[t] = f2bf(k < K_ ? kr[k*256 + col] : 0.0f);
        } else {
            int q = t - 256*KP;
            int col = q / KP, k = q % KP;
            wc_t[q] = f2bf(k < K_ ? kc[k*128 + col] : 0.0f);
        }
        return;
    }
    int wid  = (blockIdx.x * blockDim.x + threadIdx.x) >> 6;  // row of support
    int lane = threadIdx.x & 63;
    if (wid >= N_) return;
    const float* row = sup + (size_t)wid * N_;
    int base = 0;
    for (int step = 0; step < N_/64; ++step){
        int j = step*64 + lane;
        float v = row[j];
        unsigned long long m = __ballot(v != 0.0f);
        int pos = base + __popcll(m & ((1ull << lane) - 1ull));
        if (v != 0.0f && pos < CAP){
            vals[wid*CAP + pos] = v; cols[wid*CAP + pos] = j;
            if (pos < 16) packed[wid*16 + pos] = (u32)f2h(v) | ((u32)j << 16);
        }
        base += __popcll(m);
    }
    int cnt = base < CAP ? base : CAP;
    for (int p = cnt + lane; p < CAP; p += 64){
        vals[wid*CAP + p] = 0.0f;
        cols[wid*CAP + p] = 0;
        if (p < 16) packed[wid*16 + p] = 0;
    }
    if (lane == 0) nnz[wid] = (cnt + 3) & ~3;   // padded count for tail loop
}

// ========= LDS-staged SpMM: 32-col chunks, f16 staging, dot2 gather =========
#define GQD8(E0, E1)                                                           \
    {   u32 wp = __builtin_amdgcn_perm((E1), (E0), 0x05040100u);               \
        int c0 = (int)((E0) >> 16), c1 = (int)((E1) >> 16);                    \
        uint4 h0 = *(const uint4*)(s16 + c0*32 + cq*8);                        \
        uint4 h1 = *(const uint4*)(s16 + c1*32 + cq*8);                        \
        u32 p0 = __builtin_amdgcn_perm(h1.x, h0.x, 0x05040100u);               \
        u32 p1 = __builtin_amdgcn_perm(h1.x, h0.x, 0x07060302u);               \
        u32 p2 = __builtin_amdgcn_perm(h1.y, h0.y, 0x05040100u);               \
        u32 p3 = __builtin_amdgcn_perm(h1.y, h0.y, 0x07060302u);               \
        u32 p4 = __builtin_amdgcn_perm(h1.z, h0.z, 0x05040100u);               \
        u32 p5 = __builtin_amdgcn_perm(h1.z, h0.z, 0x07060302u);               \
        u32 p6 = __builtin_amdgcn_perm(h1.w, h0.w, 0x05040100u);               \
        u32 p7 = __builtin_amdgcn_perm(h1.w, h0.w, 0x07060302u);               \
        a0 = dot2_(wp, p0, a0); a1 = dot2_(wp, p1, a1);                        \
        a2 = dot2_(wp, p2, a2); a3 = dot2_(wp, p3, a3);                        \
        a4 = dot2_(wp, p4, a4); a5 = dot2_(wp, p5, a5);                        \
        a6 = dot2_(wp, p6, a6); a7 = dot2_(wp, p7, a7); }

#define GQH8(JJ, WW)                                                           \
    {   uint4 hh = *(const uint4*)(s16 + (int)(JJ)*32 + cq*8);                 \
        a0 = fmaf((WW), h2f_lo(hh.x), a0); a1 = fmaf((WW), h2f_hi(hh.x), a1);  \
        a2 = fmaf((WW), h2f_lo(hh.y), a2); a3 = fmaf((WW), h2f_hi(hh.y), a3);  \
        a4 = fmaf((WW), h2f_lo(hh.z), a4); a5 = fmaf((WW), h2f_hi(hh.z), a5);  \
        a6 = fmaf((WW), h2f_lo(hh.w), a6); a7 = fmaf((WW), h2f_hi(hh.w), a7); }

#define GATHER32(STORE_EXPR)                                                   \
    {   const int cq  = tid & 3;                                               \
        const int nb0 = tid >> 2;                                              \
        const u32* ep_ = packed + nb0*16;                                      \
        uint4 n0 = *(const uint4*)(ep_);                                       \
        uint4 n1 = *(const uint4*)(ep_ + 4);                                   \
        uint4 n2 = *(const uint4*)(ep_ + 8);                                   \
        uint4 n3 = *(const uint4*)(ep_ + 12);                                  \
        int cn = nnz[nb0];                                                     \
        _Pragma("unroll")                                                      \
        for (int i = 0; i < 8; ++i){                                           \
            int node = nb0 + i*128;                                            \
            uint4 e0 = n0, e1 = n1, e2 = n2, e3 = n3;                          \
            int c = cn;                                                        \
            if (i < 7){                                                        \
                const u32* epn = packed + (node + 128)*16;                     \
                n0 = *(const uint4*)(epn);                                     \
                n1 = *(const uint4*)(epn + 4);                                 \
                n2 = *(const uint4*)(epn + 8);                                 \
                n3 = *(const uint4*)(epn + 12);                                \
                cn = nnz[node + 128];                                          \
            }                                                                  \
            float a0=0.f,a1=0.f,a2=0.f,a3=0.f,a4=0.f,a5=0.f,a6=0.f,a7=0.f;     \
            GQD8(e0.x, e0.y) GQD8(e0.z, e0.w)                                  \
            GQD8(e1.x, e1.y) GQD8(e1.z, e1.w)                                  \
            GQD8(e2.x, e2.y) GQD8(e2.z, e2.w)                                  \
            GQD8(e3.x, e3.y) GQD8(e3.z, e3.w)                                  \
            if (c > 16){                                                       \
                const float* vt = vals + node*CAP;                             \
                const int*   ct = cols + node*CAP;                             \
                for (int t0 = 16; t0 < c; t0 += 4){                            \
                    float4 wvt = *(const float4*)(vt + t0);                    \
                    int4   jvt = *(const int4*)(ct + t0);                      \
                    GQH8(jvt.x, wvt.x) GQH8(jvt.y, wvt.y)                      \
                    GQH8(jvt.z, wvt.z) GQH8(jvt.w, wvt.w)                      \
                }                                                              \
            }                                                                  \
            size_t m = (size_t)(b<<10) + node;                                 \
            uint4 pv; pv.x = (u32)f2bf(a0) | ((u32)f2bf(a1) << 16);            \
            pv.y = (u32)f2bf(a2) | ((u32)f2bf(a3) << 16);                      \
            pv.z = (u32)f2bf(a4) | ((u32)f2bf(a5) << 16);                      \
            pv.w = (u32)f2bf(a6) | ((u32)f2bf(a7) << 16);                      \
            STORE_EXPR;                                                        \
        }                                                                      \
    }

// --- yb variant: 16 cols, stride-20 layout ----------------------------------
#define GQD4Y(E0, E1)                                                          \
    {   u32 wp = __builtin_amdgcn_perm((E1), (E0), 0x05040100u);               \
        int c0 = (int)((E0) >> 16), c1 = (int)((E1) >> 16);                    \
        uint2 ha = *(const uint2*)(s16 + c0*20 + cq*4);                        \
        uint2 hb = *(const uint2*)(s16 + c1*20 + cq*4);                        \
        u32 p0 = __builtin_amdgcn_perm(hb.x, ha.x, 0x05040100u);               \
        u32 p1 = __builtin_amdgcn_perm(hb.x, ha.x, 0x07060302u);               \
        u32 p2 = __builtin_amdgcn_perm(hb.y, ha.y, 0x05040100u);               \
        u32 p3 = __builtin_amdgcn_perm(hb.y, ha.y, 0x07060302u);               \
        a0 = dot2_(wp, p0, a0); a1 = dot2_(wp, p1, a1);                        \
        a2 = dot2_(wp, p2, a2); a3 = dot2_(wp, p3, a3); }

#define GQH4Y(JJ, WW)                                                          \
    {   uint2 hh = *(const uint2*)(s16 + (int)(JJ)*20 + cq*4);                 \
        a0 = fmaf((WW), h2f_lo(hh.x), a0); a1 = fmaf((WW), h2f_hi(hh.x), a1);  \
        a2 = fmaf((WW), h2f_lo(hh.y), a2); a3 = fmaf((WW), h2f_hi(hh.y), a3); }

// ---------------- K1: agg[:,0:144] = support @ [y_basis | hx]  (bf16) -------
__global__ __launch_bounds__(512, 4) void k_spmm1(
        const float* __restrict__ x, const float* __restrict__ hx,
        const u32* __restrict__ packed,
        const float* __restrict__ vals, const int* __restrict__ cols,
        const int* __restrict__ nnz, u16* __restrict__ agg)
{
    __shared__ u16 s16[1024*32];           // 64 KB (f16)
    const int id  = blockIdx.x;
    const int tid = threadIdx.x;

    if (id < 512){
        const int chunk = id & 3;
        const int b     = id >> 2;
        const int cb    = 16 + chunk*32;   // hx cols 16..143, always full width
        for (int q = tid; q < 4096; q += 512){
            int row = q >> 2, part = q & 3;
            const float* src = &hx[((size_t)((b<<10)+row))*128 + (cb-16) + part*8];
            float4 va = *(const float4*)src, vb = *(const float4*)(src + 4);
            uint4 pk;
            pk.x = pkrtz(va.x, va.y); pk.y = pkrtz(va.z, va.w);
            pk.z = pkrtz(vb.x, vb.y); pk.w = pkrtz(vb.z, vb.w);
            *(uint4*)(s16 + row*32 + part*8) = pk;
        }
        __syncthreads();
        GATHER32(*(uint4*)&agg[m*KP + cb + cq*8] = pv)
    } else {
        const int b = id - 512;            // yb block: cols 0..15
        for (int q = tid; q < 2048; q += 512){
            int row = q >> 1, half = q & 1;
            const float* src = &x[((size_t)((b<<10)+row))*16 + half*8];
            float4 va = *(const float4*)src, vb = *(const float4*)(src + 4);
            u16* dst = s16 + row*20 + half*8;
            *(uint2*)dst       = make_uint2(pkrtz(va.x,va.y), pkrtz(va.z,va.w));
            *(uint2*)(dst + 4) = make_uint2(pkrtz(vb.x,vb.y), pkrtz(vb.z,vb.w));
        }
        __syncthreads();
        {
            const int cq  = tid & 3;
            const int nb0 = tid >> 2;
            const u32* ep_ = packed + nb0*16;
            uint4 n0 = *(const uint4*)(ep_);
            uint4 n1 = *(const uint4*)(ep_ + 4);
            uint4 n2 = *(const uint4*)(ep_ + 8);
            uint4 n3 = *(const uint4*)(ep_ + 12);
            int cn = nnz[nb0];
            #pragma unroll
            for (int i = 0; i < 8; ++i){
                int node = nb0 + i*128;
                uint4 e0 = n0, e1 = n1, e2 = n2, e3 = n3;
                int c = cn;
                if (i < 7){
                    const u32* epn = packed + (node + 128)*16;
                    n0 = *(const uint4*)(epn);
                    n1 = *(const uint4*)(epn + 4);
                    n2 = *(const uint4*)(epn + 8);
                    n3 = *(const uint4*)(epn + 12);
                    cn = nnz[node + 128];
                }
                float a0=0.f,a1=0.f,a2=0.f,a3=0.f;
                GQD4Y(e0.x, e0.y) GQD4Y(e0.z, e0.w)
                GQD4Y(e1.x, e1.y) GQD4Y(e1.z, e1.w)
                GQD4Y(e2.x, e2.y) GQD4Y(e2.z, e2.w)
                GQD4Y(e3.x, e3.y) GQD4Y(e3.z, e3.w)
                if (c > 16){
                    const float* vt = vals + node*CAP;
                    const int*   ct = cols + node*CAP;
                    for (int t0 = 16; t0 < c; t0 += 4){
                        float4 wvt = *(const float4*)(vt + t0);
                        int4   jvt = *(const int4*)(ct + t0);
                        GQH4Y(jvt.x, wvt.x) GQH4Y(jvt.y, wvt.y)
                        GQH4Y(jvt.z, wvt.z) GQH4Y(jvt.w, wvt.w)
                    }
                }
                size_t m = (size_t)(b<<10) + node;
                ushort4 pv; pv.x = f2bf(a0); pv.y = f2bf(a1);
                pv.z = f2bf(a2); pv.w = f2bf(a3);
                *(ushort4*)&agg[m*KP + cq*4] = pv;
            }
        }
    }
}

// ---------------- K3: agg[:,16:144] = support @ (r * hx)  (bf16) ------------
__global__ __launch_bounds__(512, 4) void k_spmm2(
        const u16* __restrict__ value, const float* __restrict__ hx,
        const u32* __restrict__ packed,
        const float* __restrict__ vals, const int* __restrict__ cols,
        const int* __restrict__ nnz, u16* __restrict__ agg)
{
    __shared__ u16 s16[1024*32];           // 64 KB (f16)
    const int chunk = blockIdx.x;          // 0..3
    const int b     = blockIdx.y;
    const int tid   = threadIdx.x;
    const int cb    = chunk * 32;

    for (int q = tid; q < 4096; q += 512){
        int row = q >> 2, part = q & 3;
        size_t nb = (size_t)((b<<10)+row);
        int hxcol = cb + part*8;
        float4 h0 = *(const float4*)&hx[nb*128 + hxcol];
        float4 h1 = *(const float4*)&hx[nb*128 + hxcol + 4];
        ushort4 r0 = *(const ushort4*)&value[nb*256 + hxcol];      // r cols
        ushort4 r1 = *(const ushort4*)&value[nb*256 + hxcol + 4];
        uint4 pk;
        pk.x = pkrtz(bf2f(r0.x)*h0.x, bf2f(r0.y)*h0.y);
        pk.y = pkrtz(bf2f(r0.z)*h0.z, bf2f(r0.w)*h0.w);
        pk.z = pkrtz(bf2f(r1.x)*h1.x, bf2f(r1.y)*h1.y);
        pk.w = pkrtz(bf2f(r1.z)*h1.z, bf2f(r1.w)*h1.w);
        *(uint4*)(s16 + row*32 + part*8) = pk;
    }
    __syncthreads();

    GATHER32(*(uint4*)&agg[m*KP + D_ + cb + cq*8] = pv)
}

// ---------------- K2: value = sigmoid(agg @ kernel_r) -> bf16 ---------------
__global__ __launch_bounds__(256) void k_gemm1(const u16* __restrict__ agg,
        const u16* __restrict__ wt, u16* __restrict__ value)
{
    __shared__ u16 a_s[128*72];
    __shared__ u16 w_s[128*72];
    const int rb = blockIdx.x * 128, cb = blockIdx.y * 128;
    const int tid = threadIdx.x;
    const int wid = tid >> 6, lane = tid & 63;
    const int wr = (wid >> 1) * 64, wc = (wid & 1) * 64;
    const int lrow = lane & 15, lk = (lane >> 4) * 8;
    f32x4 acc[4][4] = {};
    for (int kb = 0; kb < KP; kb += 64){
        __syncthreads();
        #pragma unroll
        for (int i2 = 0; i2 < 4; ++i2){       // A-stage (zero K-pad)
            int q = tid + i2*256;
            int r_ = q >> 3, sl = q & 7;
            uint4 v = {0,0,0,0};
            if (kb + sl*8 < K_)
                v = *(const uint4*)(agg + (size_t)(rb+r_)*KP + kb + sl*8);
            *(uint4*)(a_s + r_*72 + sl*8) = v;
        }
        #pragma unroll
        for (int i2 = 0; i2 < 4; ++i2){       // W-stage
            int q = tid + i2*256;
            int r_ = q >> 3, sl = q & 7;
            uint4 v = *(const uint4*)(wt + (size_t)(cb+r_)*KP + kb + sl*8);
            *(uint4*)(w_s + r_*72 + sl*8) = v;
        }
        __syncthreads();
        #pragma unroll
        for (int ks = 0; ks < 2; ++ks){
            bf16x8 af[4], bfv[4];
            #pragma unroll
            for (int f = 0; f < 4; ++f){
                af[f]  = *(const bf16x8*)(a_s + (wr + f*16 + lrow)*72 + ks*32 + lk);
                bfv[f] = *(const bf16x8*)(w_s + (wc + f*16 + lrow)*72 + ks*32 + lk);
            }
            #pragma unroll
            for (int fr = 0; fr < 4; ++fr)
                #pragma unroll
                for (int fc = 0; fc < 4; ++fc)
                    acc[fr][fc] = __builtin_amdgcn_mfma_f32_16x16x32_bf16(
                        af[fr], bfv[fc], acc[fr][fc], 0, 0, 0);
        }
    }
    const int rg = (lane >> 4) * 4;
    #pragma unroll
    for (int fr = 0; fr < 4; ++fr)
        #pragma unroll
        for (int fc = 0; fc < 4; ++fc)
            #pragma unroll
            for (int j = 0; j < 4; ++j){
                int row = rb + wr + fr*16 + rg + j;
                int col = cb + wc + fc*16 + lrow;
                value[(size_t)row*256 + col] = f2bf(sig_(acc[fr][fc][j]));
            }
}

// ---------------- K4: c=tanh(agg@kernel_c); new_state = hx*u + c*(1-u) -----
__global__ __launch_bounds__(256) void k_gemm2(const u16* __restrict__ agg,
        const u16* __restrict__ wt, const float* __restrict__ hx,
        const u16* value, float* ns_out)
{
    __shared__ u16 a_s[128*72];
    __shared__ u16 w_s[128*72];
    const int rb = blockIdx.x * 128;
    const int tid = threadIdx.x;
    const int wid = tid >> 6, lane = tid & 63;
    const int wr = (wid >> 1) * 64, wc = (wid & 1) * 64;
    const int lrow = lane & 15, lk = (lane >> 4) * 8;
    f32x4 acc[4][4] = {};
    for (int kb = 0; kb < KP; kb += 64){
        __syncthreads();
        #pragma unroll
        for (int i2 = 0; i2 < 4; ++i2){       // A-stage (zero K-pad)
            int q = tid + i2*256;
            int r_ = q >> 3, sl = q & 7;
            uint4 v = {0,0,0,0};
            if (kb + sl*8 < K_)
                v = *(const uint4*)(agg + (size_t)(rb+r_)*KP + kb + sl*8);
            *(uint4*)(a_s + r_*72 + sl*8) = v;
        }
        #pragma unroll
        for (int i2 = 0; i2 < 4; ++i2){       // W-stage
            int q = tid + i2*256;
            int r_ = q >> 3, sl = q & 7;
            uint4 v = *(const uint4*)(wt + (size_t)r_*KP + kb + sl*8);
            *(uint4*)(w_s + r_*72 + sl*8) = v;
        }
        __syncthreads();
        #pragma unroll
        for (int ks = 0; ks < 2; ++ks){
            bf16x8 af[4], bfv[4];
            #pragma unroll
            for (int f = 0; f < 4; ++f){
                af[f]  = *(const bf16x8*)(a_s + (wr + f*16 + lrow)*72 + ks*32 + lk);
                bfv[f] = *(const bf16x8*)(w_s + (wc + f*16 + lrow)*72 + ks*32 + lk);
            }
            #pragma unroll
            for (int fr = 0; fr < 4; ++fr)
                #pragma unroll
                for (int fc = 0; fc < 4; ++fc)
                    acc[fr][fc] = __builtin_amdgcn_mfma_f32_16x16x32_bf16(
                        af[fr], bfv[fc], acc[fr][fc], 0, 0, 0);
        }
    }
    const int rg = (lane >> 4) * 4;
    float ov[4][4][4];
    #pragma unroll
    for (int fr = 0; fr < 4; ++fr)
        #pragma unroll
        for (int fc = 0; fc < 4; ++fc)
            #pragma unroll
            for (int j = 0; j < 4; ++j){
                int row = rb + wr + fr*16 + rg + j;
                int col = wc + fc*16 + lrow;
                float u = bf2f(value[(size_t)row*256 + 128 + col]);
                float h = hx[(size_t)row*128 + col];
                float c = tanhf(acc[fr][fc][j]);
                ov[fr][fc][j] = h*u + c*(1.0f - u);
            }
    __syncthreads();   // all u-loads complete before anyone overwrites the slot
    #pragma unroll
    for (int fr = 0; fr < 4; ++fr)
        #pragma unroll
        for (int fc = 0; fc < 4; ++fc)
            #pragma unroll
            for (int j = 0; j < 4; ++j){
                int row = rb + wr + fr*16 + rg + j;
                int col = wc + fc*16 + lrow;
                ns_out[(size_t)row*128 + col] = ov[fr][fc][j];
            }
}

// ------- K5: o = [new_state | y_basis] @ w_out + b_out + new_delta; + nd ----
__global__ __launch_bounds__(256) void k_out(const float* __restrict__ ns,
        const float* __restrict__ x, const float* __restrict__ delta,
        const float* __restrict__ wo, const float* __restrict__ bo,
        const float* __restrict__ wb, const float* __restrict__ bb,
        const float* __restrict__ lam,
        float* __restrict__ o, float* __restrict__ nd_out)
{
    __shared__ float ns_s[64][132];
    __shared__ float yb_s[64][20];
    __shared__ float yr_s[64][20];
    __shared__ float w_s[144][16];
    __shared__ float wb_s[16][16];
    __shared__ float bo_s[16], bb_s[16];
    int rowbase = blockIdx.x * 64;
    int tid = threadIdx.x;
    const float* yr = x + (size_t)M_ * D_;      // x[1] = y_res
    #pragma unroll
    for (int jj = 0; jj < 8; ++jj){
        int q = tid + 256*jj;           // 2048 float4 = 64 rows x 128
        int row = q >> 5, c4 = (q & 31) * 4;
        *(float4*)&ns_s[row][c4] = *(const float4*)&ns[(size_t)(rowbase + row)*U_ + c4];
    }
    {
        int row = tid >> 2, c4 = (tid & 3) * 4;   // 256 float4 = 64 rows x 16
        *(float4*)&yb_s[row][c4] = *(const float4*)&x[(size_t)(rowbase + row)*D_ + c4];
        *(float4*)&yr_s[row][c4] = *(const float4*)&yr[(size_t)(rowbase + row)*D_ + c4];
    }
    #pragma unroll
    for (int jj = 0; jj < 3; ++jj){
        int q = tid + 256*jj;
        if (q < 576){ int k = q >> 2, d4 = (q & 3) * 4;
            *(float4*)&w_s[k][d4] = *(const float4*)&wo[k*D_ + d4]; }
    }
    wb_s[tid >> 4][tid & 15] = wb[tid];          // 256 = 16x16
    if (tid < 16){ bo_s[tid] = bo[tid]; bb_s[tid] = bb[tid]; }
    __syncthreads();
    int row = tid >> 2, d0 = (tid & 3) * 4;
    float4 acc = make_float4(0.f,0.f,0.f,0.f);
    for (int k = 0; k < U_; ++k){
        float cs = ns_s[row][k];
        float4 w = *(const float4*)&w_s[k][d0];
        acc.x = fmaf(cs, w.x, acc.x); acc.y = fmaf(cs, w.y, acc.y);
        acc.z = fmaf(cs, w.z, acc.z); acc.w = fmaf(cs, w.w, acc.w);
    }
    #pragma unroll
    for (int k = 0; k < D_; ++k){
        float cs = yb_s[row][k];
        float4 w = *(const float4*)&w_s[U_ + k][d0];
        acc.x = fmaf(cs, w.x, acc.x); acc.y = fmaf(cs, w.y, acc.y);
        acc.z = fmaf(cs, w.z, acc.z); acc.w = fmaf(cs, w.w, acc.w);
    }
    float4 dacc = make_float4(bb_s[d0], bb_s[d0+1], bb_s[d0+2], bb_s[d0+3]);
    #pragma unroll
    for (int k = 0; k < D_; ++k){
        float yv = yr_s[row][k];
        float4 w = *(const float4*)&wb_s[k][d0];
        dacc.x = fmaf(yv, w.x, dacc.x); dacc.y = fmaf(yv, w.y, dacc.y);
        dacc.z = fmaf(yv, w.z, dacc.z); dacc.w = fmaf(yv, w.w, dacc.w);
    }
    size_t off = (size_t)(rowbase + row)*D_ + d0;
    float4 dl = *(const float4*)&delta[off];
    float lm = lam[0];
    float nd4[4];
    float yv4[4] = {yr_s[row][d0], yr_s[row][d0+1], yr_s[row][d0+2], yr_s[row][d0+3]};
    float dv4[4] = {fmaxf(dacc.x,0.f), fmaxf(dacc.y,0.f), fmaxf(dacc.z,0.f), fmaxf(dacc.w,0.f)};
    float dl4[4] = {dl.x, dl.y, dl.z, dl.w};
    #pragma unroll
    for (int j = 0; j < 4; ++j){
        float pt = sig_(yv4[j] + 0.5f * sqrtf(fabsf(dl4[j] + 1e-9f)));
        nd4[j] = lm * (2.0f * pt - 1.0f) * dv4[j];
    }
    float4 bov = *(const float4*)&bo_s[d0];
    float4 ov = make_float4(acc.x + bov.x + nd4[0], acc.y + bov.y + nd4[1],
                            acc.z + bov.z + nd4[2], acc.w + bov.w + nd4[3]);
    *(float4*)&nd_out[off] = make_float4(nd4[0], nd4[1], nd4[2], nd4[3]);
    *(float4*)&o[off] = ov;
}

extern "C" void kernel_launch(void* const* d_in, const int* in_sizes, int n_in,
                              void* d_out, int out_size, void* d_ws, size_t ws_size,
                              hipStream_t stream)
{
    const float* x        = (const float*)d_in[0];
    const float* hx       = (const float*)d_in[1];
    const float* delta    = (const float*)d_in[2];
    const float* support  = (const float*)d_in[3];
    const float* kernel_r = (const float*)d_in[4];
    const float* kernel_c = (const float*)d_in[5];
    const float* w_out    = (const float*)d_in[6];
    const float* b_out    = (const float*)d_in[7];
    const float* w_basis  = (const float*)d_in[8];
    const float* b_basis  = (const float*)d_in[9];
    const float* lam      = (const float*)d_in[10];

    float* out = (float*)d_out;
    float* o   = out;                    // (B,N,D)   2,097,152
    float* ns  = out + 2097152;          // (B,N*U)  16,777,216
    float* nd  = out + 18874368;         // (B,N,D)   2,097,152
    u16*   value = (u16*)ns;             // bf16 [M][256] lives in ns slot

    char* ws = (char*)d_ws;
    float* ell_vals = (float*)ws;                       // 1024*48*4 = 196608
    int*   ell_cols = (int*)(ws + 196608);              // 196608
    int*   ell_nnz  = (int*)(ws + 393216);              // 4096
    u32*   ell_pk   = (u32*)(ws + 397312);              // 1024*16*4 = 65536
    u16*   agg      = (u16*)(ws + (1 << 20));           // [M][192] bf16 = 50.3 MB
    u16*   wr_t     = (u16*)(ws + (1 << 20) + (size_t)M_*KP*2);          // 256*192
    u16*   wc_t     = wr_t + 256*KP;                                     // 128*192

    k_ellprep<<<544, 256, 0, stream>>>(support, kernel_r, kernel_c,
                                       ell_vals, ell_cols, ell_nnz, ell_pk,
                                       wr_t, wc_t);
    k_spmm1<<<640, 512, 0, stream>>>(x, hx, ell_pk,
                                     ell_vals, ell_cols, ell_nnz, agg);
    k_gemm1<<<dim3(M_/128, 2), 256, 0, stream>>>(agg, wr_t, value);
    k_spmm2<<<dim3(4,128), 512, 0, stream>>>(value, hx, ell_pk,
                                             ell_vals, ell_cols, ell_nnz, agg);
    k_gemm2<<<M_/128, 256, 0, stream>>>(agg, wc_t, hx, value, ns);
    k_out  <<<M_/64, 256, 0, stream>>>(ns, x, delta, w_out, b_out,
                                       w_basis, b_basis, lam, o, nd);
}